// Round 1
// 523.110 us; speedup vs baseline: 1.0349x; 1.0349x over previous
//
#include <hip/hip_runtime.h>
#include <stdint.h>

#define NTOK 4096   // B*S tokens
#define DIM  1024   // model dim
#define NEXP 8      // experts
#define HID  4096   // expert hidden
#define CAP  1024   // capacity per expert

typedef __bf16 bf16x8 __attribute__((ext_vector_type(8)));
typedef float  f32x4  __attribute__((ext_vector_type(4)));

__device__ __forceinline__ unsigned short f2bf(float f) {
  unsigned int u = __float_as_uint(f);
  return (unsigned short)((u + 0x7fffu + ((u >> 16) & 1u)) >> 16);  // RNE
}

__device__ __forceinline__ float bf2f(unsigned int bits16) {
  return __uint_as_float(bits16 << 16);
}

__device__ __forceinline__ void load_lds16(const void* g, void* l) {
  __builtin_amdgcn_global_load_lds(
      (__attribute__((address_space(1))) void*)g,
      (__attribute__((address_space(3))) void*)l,
      16, 0, 0);
}

// ---------------- 1. gating ----------------
__global__ void gating_kernel(const float* __restrict__ x, const float* __restrict__ wg,
                              int* __restrict__ tok_e, float* __restrict__ tok_g) {
  const int t = blockIdx.x;
  const int l = threadIdx.x;
  float acc[NEXP];
#pragma unroll
  for (int e = 0; e < NEXP; ++e) acc[e] = 0.f;

  const float4* x4  = (const float4*)(x + (size_t)t * DIM);
  const float4* wg4 = (const float4*)wg;
#pragma unroll
  for (int i = 0; i < 4; ++i) {
    int dq = i * 64 + l;
    float4 xv = x4[dq];
    float xs[4] = {xv.x, xv.y, xv.z, xv.w};
#pragma unroll
    for (int c = 0; c < 4; ++c) {
      int d = dq * 4 + c;
      float4 wa = wg4[d * 2], wb = wg4[d * 2 + 1];
      acc[0] += xs[c] * wa.x; acc[1] += xs[c] * wa.y;
      acc[2] += xs[c] * wa.z; acc[3] += xs[c] * wa.w;
      acc[4] += xs[c] * wb.x; acc[5] += xs[c] * wb.y;
      acc[6] += xs[c] * wb.z; acc[7] += xs[c] * wb.w;
    }
  }
#pragma unroll
  for (int off = 32; off; off >>= 1)
#pragma unroll
    for (int e = 0; e < NEXP; ++e) acc[e] += __shfl_xor(acc[e], off);

  if (l == 0) {
    float m = acc[0];
#pragma unroll
    for (int e = 1; e < NEXP; ++e) m = fmaxf(m, acc[e]);
    float p[NEXP];
#pragma unroll
    for (int e = 0; e < NEXP; ++e) p[e] = __expf(acc[e] - m);
    int e0 = 0; float b0 = p[0];
#pragma unroll
    for (int e = 1; e < NEXP; ++e) if (p[e] > b0) { b0 = p[e]; e0 = e; }
    int e1 = -1; float b1v = -1.f;
#pragma unroll
    for (int e = 0; e < NEXP; ++e) if (e != e0 && p[e] > b1v) { b1v = p[e]; e1 = e; }
    float inv = 1.f / (b0 + b1v);
    tok_e[2 * t] = e0; tok_e[2 * t + 1] = e1;
    tok_g[2 * t] = b0 * inv; tok_g[2 * t + 1] = b1v * inv;
  }
}

// ---------------- 2. GShard slot-major cumsum ----------------
__global__ void scan_kernel(const int* __restrict__ tok_e, int* __restrict__ tok_loc,
                            int* __restrict__ slot_map) {
  const int l = threadIdx.x;
  const unsigned long long below = (1ull << l) - 1ull;
  int base[NEXP];
#pragma unroll
  for (int e = 0; e < NEXP; ++e) base[e] = 0;

  int nxt = tok_e[((0 * 64 + l) & (NTOK - 1)) * 2 + ((0 * 64 + l) >> 12)];
  for (int it = 0; it < 128; ++it) {
    int e = nxt;
    if (it + 1 < 128) {
      int g2 = (it + 1) * 64 + l;
      nxt = tok_e[(g2 & (NTOK - 1)) * 2 + (g2 >> 12)];
    }
    int loc = 0;
#pragma unroll
    for (int ex = 0; ex < NEXP; ++ex) {
      unsigned long long msk = __ballot(e == ex);
      int off = __popcll(msk & below);
      if (e == ex) loc = base[ex] + off;
      base[ex] += __popcll(msk);
    }
    int g = it * 64 + l;
    int k = g >> 12, t = g & (NTOK - 1);
    bool valid = loc < CAP;
    tok_loc[t * 2 + k] = valid ? loc : -1;
    if (valid) slot_map[e * CAP + loc] = t;
  }
#pragma unroll
  for (int ex = 0; ex < NEXP; ++ex) {
    int c = base[ex] < CAP ? base[ex] : CAP;
    for (int i = c + l; i < CAP; i += 64) slot_map[ex * CAP + i] = -1;
  }
}

// ---------------- 3. dispatch: gather x rows -> disp[E,CAP,D] bf16 ----------------
__global__ void dispatch_kernel(const float* __restrict__ x, const int* __restrict__ slot_map,
                                unsigned short* __restrict__ disp) {
  const int s = blockIdx.x;
  const int tid = threadIdx.x;
  int t = slot_map[s];
  uint2 o;
  if (t >= 0) {
    float4 v = ((const float4*)(x + (size_t)t * DIM))[tid];
    o.x = (unsigned)f2bf(v.x) | ((unsigned)f2bf(v.y) << 16);
    o.y = (unsigned)f2bf(v.z) | ((unsigned)f2bf(v.w) << 16);
  } else {
    o.x = 0u; o.y = 0u;
  }
  ((uint2*)(disp + (size_t)s * DIM))[tid] = o;
}

// ---------------- 4. transpose fp32 [R,C] -> bf16 [C,R] per expert ----------------
__global__ void transpose_cvt(const float* __restrict__ in, unsigned short* __restrict__ out,
                              int R, int C) {
  __shared__ float tile[64][65];
  const int e = blockIdx.z;
  const float* inp = in + (size_t)e * R * C;
  unsigned short* outp = out + (size_t)e * R * C;
  const int c0 = blockIdx.x * 64, r0 = blockIdx.y * 64;
  const int t = threadIdx.x;
#pragma unroll
  for (int i = 0; i < 4; ++i) {
    int idx = i * 256 + t;
    int r = idx >> 4, c4 = (idx & 15) * 4;
    float4 v = *(const float4*)(inp + (size_t)(r0 + r) * C + c0 + c4);
    tile[r][c4 + 0] = v.x; tile[r][c4 + 1] = v.y;
    tile[r][c4 + 2] = v.z; tile[r][c4 + 3] = v.w;
  }
  __syncthreads();
#pragma unroll
  for (int i = 0; i < 2; ++i) {
    int idx = i * 256 + t;            // 512 items: (col, 8-row group)
    int c = idx >> 3, r8 = (idx & 7) * 8;
    unsigned short s[8];
#pragma unroll
    for (int j = 0; j < 8; ++j) s[j] = f2bf(tile[r8 + j][c]);
    uint4 o;
    o.x = (unsigned)s[0] | ((unsigned)s[1] << 16);
    o.y = (unsigned)s[2] | ((unsigned)s[3] << 16);
    o.z = (unsigned)s[4] | ((unsigned)s[5] << 16);
    o.w = (unsigned)s[6] | ((unsigned)s[7] << 16);
    *(uint4*)(outp + (size_t)(c0 + c) * R + r0 + r8) = o;
  }
}

// ---------------- 5/6. bf16 MFMA GEMM: 8-phase schedule, counted vmcnt ----------
// A [M=1024][K] bf16, B [N][K] bf16, C [M][N] bf16 (bias fp32 along N).
// 512 threads = 8 waves (2M x 4N). BK=64. Half-tile slot rotation:
// per operand 4 LDS slots of (BM/2 | BN/2) x 64; slot(X(t)) = 2*(t&1)+half.
// Per K-tile: 4 phases, one (Mh,Nh) quadrant each; stage map
//   ph0->A1(t+1)  ph1->B1(t+1)  ph2->B0(t+2)  ph3->A0(t+2)
// derived so every slot overwrite is issued >=1 barrier-separated phase after
// that slot's last read.  vmcnt(LA+LB) once per K-tile (never 0) publishes the
// next tile's data (checked by in-flight counting incl. prologue).
// LDS row swizzle: within each 128B row, chunk16 phys = logical ^ (row&7);
// staging pre-swizzles the *global* source column (global_load_lds dest must
// stay linear), fragment reads XOR it back.  Same as prior verified kernel.
template <int BM, int BN, bool RELU>
__global__ __launch_bounds__(512)
void gemm8(const unsigned short* __restrict__ A, const unsigned short* __restrict__ B,
           const float* __restrict__ bias, unsigned short* __restrict__ C,
           int N, int K) {
  constexpr int M = 1024;
  constexpr int FR = BM / 64;        // A frags per phase (per wave)
  constexpr int FC = BN / 128;       // B frags per phase (per wave)
  constexpr int ASLOT = (BM / 2) * 64;   // elems per A half-slot
  constexpr int BSLOT = (BN / 2) * 64;
  constexpr int LA = BM / 128;       // global_load_lds per thread per A half
  constexpr int LB = BN / 128;
  static_assert(LA + LB == 4 || LA + LB == 3, "vmcnt literal");

  extern __shared__ __align__(16) unsigned short smem[];
  unsigned short* As = smem;                  // 4 slots
  unsigned short* Bs = smem + 4 * ASLOT;      // 4 slots

  const int mt = M / BM;
  const int ntn = N / BN;
  const int bid = blockIdx.x;
  const int e = bid / (mt * ntn);
  const int rb = bid - e * mt * ntn;
  const int mtile = rb / ntn;
  const int ntile = rb - mtile * ntn;

  A += (size_t)e * M * K;
  B += (size_t)e * N * K;
  bias += (size_t)e * N;
  C += (size_t)e * M * N;
  const int m0 = mtile * BM;
  const int n0 = ntile * BN;

  const int tid = threadIdx.x;
  const int w = tid >> 6, lane = tid & 63;
  const int wm = w >> 2, wn = w & 3;

  // staging: per 64-row round, thread covers row w*8+(lane>>3), phys chunk lane&7,
  // loading swizzled logical chunk (lane&7)^(row&7), row&7 == lane>>3
  const int srow = lane >> 3;
  const int scol = ((lane & 7) ^ srow) * 8;
  const unsigned short* gA = A + (size_t)(m0 + w * 8 + srow) * K + scol;
  const unsigned short* gB = B + (size_t)(n0 + w * 8 + srow) * K + scol;
  const int lbase = w * 512;   // elems: w*8 rows * 64

  // fragment-read addressing (row&7 == lane&7 for all frag rows)
  const int arow0 = wm * (BM / 4) + (lane & 15);
  const int brow0 = wn * (BN / 8) + (lane & 15);
  const int c0 = (((lane >> 4) + 0) ^ (lane & 7)) * 8;
  const int c1 = (((lane >> 4) + 4) ^ (lane & 7)) * 8;

  f32x4 acc[2][2][FR][FC] = {};
  const int nt = K >> 6;

#define STAGE_A(T, MH) do {                                                        \
    const unsigned short* g_ = gA + (size_t)((MH) * (BM / 2)) * K + (size_t)(T) * 64; \
    unsigned short* l_ = &As[(2 * ((T) & 1) + (MH)) * ASLOT + lbase];              \
    _Pragma("unroll")                                                              \
    for (int q_ = 0; q_ < LA; ++q_)                                                \
      load_lds16(g_ + (size_t)q_ * 64 * K, l_ + q_ * 4096);                        \
  } while (0)

#define STAGE_B(T, NH) do {                                                        \
    const unsigned short* g_ = gB + (size_t)((NH) * (BN / 2)) * K + (size_t)(T) * 64; \
    unsigned short* l_ = &Bs[(2 * ((T) & 1) + (NH)) * BSLOT + lbase];              \
    _Pragma("unroll")                                                              \
    for (int q_ = 0; q_ < LB; ++q_)                                                \
      load_lds16(g_ + (size_t)q_ * 64 * K, l_ + q_ * 4096);                        \
  } while (0)

#define WAIT_VMN() do {                                                            \
    if constexpr (LA + LB == 4) asm volatile("s_waitcnt vmcnt(4)" ::: "memory");   \
    else                        asm volatile("s_waitcnt vmcnt(3)" ::: "memory");   \
  } while (0)

#define PHASE(MH, NH, ISVM, ...) do {                                              \
    bf16x8 af[FR][2], bfv[FC][2];                                                  \
    const unsigned short* ab_ = &As[(2 * cur + (MH)) * ASLOT + arow0 * 64];        \
    const unsigned short* bb_ = &Bs[(2 * cur + (NH)) * BSLOT + brow0 * 64];        \
    _Pragma("unroll")                                                              \
    for (int f_ = 0; f_ < FR; ++f_) {                                              \
      af[f_][0] = *(const bf16x8*)(ab_ + f_ * 1024 + c0);                          \
      af[f_][1] = *(const bf16x8*)(ab_ + f_ * 1024 + c1);                          \
    }                                                                              \
    _Pragma("unroll")                                                              \
    for (int f_ = 0; f_ < FC; ++f_) {                                              \
      bfv[f_][0] = *(const bf16x8*)(bb_ + f_ * 1024 + c0);                         \
      bfv[f_][1] = *(const bf16x8*)(bb_ + f_ * 1024 + c1);                         \
    }                                                                              \
    __VA_ARGS__                                                                    \
    __builtin_amdgcn_s_barrier();                                                  \
    asm volatile("s_waitcnt lgkmcnt(0)" ::: "memory");                             \
    __builtin_amdgcn_sched_barrier(0);                                             \
    __builtin_amdgcn_s_setprio(1);                                                 \
    _Pragma("unroll")                                                              \
    for (int f_ = 0; f_ < FR; ++f_)                                                \
      _Pragma("unroll")                                                            \
      for (int g_ = 0; g_ < FC; ++g_) {                                            \
        acc[MH][NH][f_][g_] = __builtin_amdgcn_mfma_f32_16x16x32_bf16(             \
            af[f_][0], bfv[g_][0], acc[MH][NH][f_][g_], 0, 0, 0);                  \
        acc[MH][NH][f_][g_] = __builtin_amdgcn_mfma_f32_16x16x32_bf16(             \
            af[f_][1], bfv[g_][1], acc[MH][NH][f_][g_], 0, 0, 0);                  \
      }                                                                            \
    __builtin_amdgcn_s_setprio(0);                                                 \
    if (ISVM) WAIT_VMN();                                                          \
    asm volatile("" ::: "memory");                                                 \
    __builtin_amdgcn_s_barrier();                                                  \
  } while (0)

  // prologue: A0(0),A1(0),B0(0),B1(0),B0(1),A0(1); allow last two in flight
  STAGE_A(0, 0); STAGE_A(0, 1); STAGE_B(0, 0); STAGE_B(0, 1);
  STAGE_B(1, 0); STAGE_A(1, 0);
  WAIT_VMN();
  __builtin_amdgcn_s_barrier();

  for (int t = 0; t < nt; ++t) {
    const int cur = t & 1;
    const bool s1 = (t + 1) < nt, s2 = (t + 2) < nt;
    PHASE(0, 0, false, if (s1) STAGE_A(t + 1, 1); );
    PHASE(1, 0, false, if (s1) STAGE_B(t + 1, 1); );
    PHASE(0, 1, false, if (s2) STAGE_B(t + 2, 0); );
    PHASE(1, 1, true,  if (s2) STAGE_A(t + 2, 0); );
  }

#undef PHASE
#undef WAIT_VMN
#undef STAGE_B
#undef STAGE_A

  // ---- epilogue: restage per M-half -> coalesced dwordx4 stores ----
  const int lc = lane & 15, quad = lane >> 4;
  constexpr int SW = BN + 8;              // shorts; 528B row stride, 16B aligned
  unsigned short* scr = smem;
#pragma unroll
  for (int Mh = 0; Mh < 2; ++Mh) {
    __syncthreads();
#pragma unroll
    for (int Nh = 0; Nh < 2; ++Nh)
#pragma unroll
      for (int f = 0; f < FR; ++f)
#pragma unroll
        for (int g = 0; g < FC; ++g) {
          float bv = bias[n0 + Nh * (BN / 2) + wn * (BN / 8) + g * 16 + lc];
#pragma unroll
          for (int r2 = 0; r2 < 4; ++r2) {
            float v = acc[Mh][Nh][f][g][r2] + bv;
            if (RELU) v = fmaxf(v, 0.f);
            scr[(wm * (BM / 4) + f * 16 + quad * 4 + r2) * SW +
                Nh * (BN / 2) + wn * (BN / 8) + g * 16 + lc] = f2bf(v);
          }
        }
    __syncthreads();
#pragma unroll
    for (int it = 0; it < (BM / 2) * (BN / 8) / 512; ++it) {
      const int u = it * 512 + tid;
      const int row = u / (BN / 8), seg = u % (BN / 8);
      uint4 v = *(const uint4*)&scr[row * SW + seg * 8];
      *(uint4*)&C[(size_t)(m0 + Mh * (BM / 2) + row) * N + n0 + seg * 8] = v;
    }
  }
}

// ---------------- 7. combine: gate-weighted gather (bf16 expert out) ----------------
__global__ void combine_kernel(const unsigned short* __restrict__ outb,
                               const int* __restrict__ tok_e, const int* __restrict__ tok_loc,
                               const float* __restrict__ tok_g, float* __restrict__ y) {
  const int t = blockIdx.x;
  const int tid = threadIdx.x;  // 0..255, 4 bf16 each
  int e0 = tok_e[2 * t], e1 = tok_e[2 * t + 1];
  int l0 = tok_loc[2 * t], l1 = tok_loc[2 * t + 1];
  float g0 = tok_g[2 * t], g1 = tok_g[2 * t + 1];
  float ax = 0.f, ay = 0.f, az = 0.f, aw = 0.f;
  if (l0 >= 0) {
    uint2 u = ((const uint2*)(outb + ((size_t)e0 * CAP + l0) * DIM))[tid];
    ax += g0 * bf2f(u.x & 0xffffu); ay += g0 * __uint_as_float(u.x & 0xffff0000u);
    az += g0 * bf2f(u.y & 0xffffu); aw += g0 * __uint_as_float(u.y & 0xffff0000u);
  }
  if (l1 >= 0) {
    uint2 u = ((const uint2*)(outb + ((size_t)e1 * CAP + l1) * DIM))[tid];
    ax += g1 * bf2f(u.x & 0xffffu); ay += g1 * __uint_as_float(u.x & 0xffff0000u);
    az += g1 * bf2f(u.y & 0xffffu); aw += g1 * __uint_as_float(u.y & 0xffff0000u);
  }
  float4 o; o.x = ax; o.y = ay; o.z = az; o.w = aw;
  ((float4*)(y + (size_t)t * DIM))[tid] = o;
}

extern "C" void kernel_launch(void* const* d_in, const int* in_sizes, int n_in,
                              void* d_out, int out_size, void* d_ws, size_t ws_size,
                              hipStream_t stream) {
  const float* x  = (const float*)d_in[0];
  const float* wg = (const float*)d_in[1];
  const float* w1 = (const float*)d_in[2];
  const float* b1 = (const float*)d_in[3];
  const float* w2 = (const float*)d_in[4];
  const float* b2 = (const float*)d_in[5];
  float* y = (float*)d_out;

  char* ws = (char*)d_ws;
  int*   tok_e    = (int*)(ws);
  int*   tok_loc  = (int*)(ws + 32768);
  float* tok_g    = (float*)(ws + 65536);
  int*   slot_map = (int*)(ws + 98304);
  unsigned short* disp = (unsigned short*)(ws + 131072);                      // 16 MiB
  unsigned short* wbuf = (unsigned short*)(ws + 131072 + (16ull << 20));      // 64 MiB
  unsigned short* h    = (unsigned short*)(ws + 131072 + (80ull << 20));      // 64 MiB
  unsigned short* outb = (unsigned short*)(ws + 131072 + (144ull << 20));     // 16 MiB

  // one-time: allow >64 KiB dynamic LDS for the 8-phase GEMMs
  static int att = 0;
  if (!att) {
    (void)hipFuncSetAttribute(reinterpret_cast<const void*>(&gemm8<256, 256, true>),
                              hipFuncAttributeMaxDynamicSharedMemorySize, 131072);
    (void)hipFuncSetAttribute(reinterpret_cast<const void*>(&gemm8<128, 256, false>),
                              hipFuncAttributeMaxDynamicSharedMemorySize, 98304);
    att = 1;
  }

  gating_kernel<<<NTOK, 64, 0, stream>>>(x, wg, tok_e, tok_g);
  scan_kernel<<<1, 64, 0, stream>>>(tok_e, tok_loc, slot_map);
  dispatch_kernel<<<NEXP * CAP, 256, 0, stream>>>(x, slot_map, disp);
  // w1 [E][D][H] -> wbuf [E][H][D] bf16
  transpose_cvt<<<dim3(HID / 64, DIM / 64, NEXP), 256, 0, stream>>>(w1, wbuf, DIM, HID);
  // h = relu(disp @ w1 + b1): M=1024, N=HID, K=DIM; 8*4*16 = 512 blocks
  gemm8<256, 256, true><<<NEXP * (1024 / 256) * (HID / 256), 512, 131072, stream>>>(
      disp, wbuf, b1, h, HID, DIM);
  // w2 [E][H][D] -> wbuf [E][D][H] bf16
  transpose_cvt<<<dim3(DIM / 64, HID / 64, NEXP), 256, 0, stream>>>(w2, wbuf, HID, DIM);
  // out = h @ w2 + b2: M=1024, N=DIM, K=HID; 8*8*4 = 256 blocks
  gemm8<128, 256, false><<<NEXP * (1024 / 128) * (DIM / 256), 512, 98304, stream>>>(
      h, wbuf, b2, outb, DIM, HID);
  combine_kernel<<<NTOK, 256, 0, stream>>>(outb, tok_e, tok_loc, tok_g, y);
}

// Round 3
// 522.711 us; speedup vs baseline: 1.0357x; 1.0008x over previous
//
#include <hip/hip_runtime.h>
#include <stdint.h>

#define NTOK 4096   // B*S tokens
#define DIM  1024   // model dim
#define NEXP 8      // experts
#define HID  4096   // expert hidden
#define CAP  1024   // capacity per expert

typedef __bf16 bf16x8 __attribute__((ext_vector_type(8)));
typedef float  f32x4  __attribute__((ext_vector_type(4)));
typedef float  f32x16 __attribute__((ext_vector_type(16)));

__device__ __forceinline__ unsigned short f2bf(float f) {
  unsigned int u = __float_as_uint(f);
  return (unsigned short)((u + 0x7fffu + ((u >> 16) & 1u)) >> 16);  // RNE
}

__device__ __forceinline__ float bf2f(unsigned int bits16) {
  return __uint_as_float(bits16 << 16);
}

__device__ __forceinline__ void load_lds16(const void* g, void* l) {
  __builtin_amdgcn_global_load_lds(
      (__attribute__((address_space(1))) void*)g,
      (__attribute__((address_space(3))) void*)l,
      16, 0, 0);
}

// ---------------- 1. gating ----------------
__global__ void gating_kernel(const float* __restrict__ x, const float* __restrict__ wg,
                              int* __restrict__ tok_e, float* __restrict__ tok_g) {
  const int t = blockIdx.x;
  const int l = threadIdx.x;
  float acc[NEXP];
#pragma unroll
  for (int e = 0; e < NEXP; ++e) acc[e] = 0.f;

  const float4* x4  = (const float4*)(x + (size_t)t * DIM);
  const float4* wg4 = (const float4*)wg;
#pragma unroll
  for (int i = 0; i < 4; ++i) {
    int dq = i * 64 + l;
    float4 xv = x4[dq];
    float xs[4] = {xv.x, xv.y, xv.z, xv.w};
#pragma unroll
    for (int c = 0; c < 4; ++c) {
      int d = dq * 4 + c;
      float4 wa = wg4[d * 2], wb = wg4[d * 2 + 1];
      acc[0] += xs[c] * wa.x; acc[1] += xs[c] * wa.y;
      acc[2] += xs[c] * wa.z; acc[3] += xs[c] * wa.w;
      acc[4] += xs[c] * wb.x; acc[5] += xs[c] * wb.y;
      acc[6] += xs[c] * wb.z; acc[7] += xs[c] * wb.w;
    }
  }
#pragma unroll
  for (int off = 32; off; off >>= 1)
#pragma unroll
    for (int e = 0; e < NEXP; ++e) acc[e] += __shfl_xor(acc[e], off);

  if (l == 0) {
    float m = acc[0];
#pragma unroll
    for (int e = 1; e < NEXP; ++e) m = fmaxf(m, acc[e]);
    float p[NEXP];
#pragma unroll
    for (int e = 0; e < NEXP; ++e) p[e] = __expf(acc[e] - m);
    int e0 = 0; float b0 = p[0];
#pragma unroll
    for (int e = 1; e < NEXP; ++e) if (p[e] > b0) { b0 = p[e]; e0 = e; }
    int e1 = -1; float b1v = -1.f;
#pragma unroll
    for (int e = 0; e < NEXP; ++e) if (e != e0 && p[e] > b1v) { b1v = p[e]; e1 = e; }
    float inv = 1.f / (b0 + b1v);
    tok_e[2 * t] = e0; tok_e[2 * t + 1] = e1;
    tok_g[2 * t] = b0 * inv; tok_g[2 * t + 1] = b1v * inv;
  }
}

// ---------------- 2. GShard slot-major cumsum ----------------
__global__ void scan_kernel(const int* __restrict__ tok_e, int* __restrict__ tok_loc,
                            int* __restrict__ slot_map) {
  const int l = threadIdx.x;
  const unsigned long long below = (1ull << l) - 1ull;
  int base[NEXP];
#pragma unroll
  for (int e = 0; e < NEXP; ++e) base[e] = 0;

  int nxt = tok_e[((0 * 64 + l) & (NTOK - 1)) * 2 + ((0 * 64 + l) >> 12)];
  for (int it = 0; it < 128; ++it) {
    int e = nxt;
    if (it + 1 < 128) {
      int g2 = (it + 1) * 64 + l;
      nxt = tok_e[(g2 & (NTOK - 1)) * 2 + (g2 >> 12)];
    }
    int loc = 0;
#pragma unroll
    for (int ex = 0; ex < NEXP; ++ex) {
      unsigned long long msk = __ballot(e == ex);
      int off = __popcll(msk & below);
      if (e == ex) loc = base[ex] + off;
      base[ex] += __popcll(msk);
    }
    int g = it * 64 + l;
    int k = g >> 12, t = g & (NTOK - 1);
    bool valid = loc < CAP;
    tok_loc[t * 2 + k] = valid ? loc : -1;
    if (valid) slot_map[e * CAP + loc] = t;
  }
#pragma unroll
  for (int ex = 0; ex < NEXP; ++ex) {
    int c = base[ex] < CAP ? base[ex] : CAP;
    for (int i = c + l; i < CAP; i += 64) slot_map[ex * CAP + i] = -1;
  }
}

// ---------------- 3. dispatch: gather x rows -> disp[E,CAP,D] bf16 ----------------
__global__ void dispatch_kernel(const float* __restrict__ x, const int* __restrict__ slot_map,
                                unsigned short* __restrict__ disp) {
  const int s = blockIdx.x;
  const int tid = threadIdx.x;
  int t = slot_map[s];
  uint2 o;
  if (t >= 0) {
    float4 v = ((const float4*)(x + (size_t)t * DIM))[tid];
    o.x = (unsigned)f2bf(v.x) | ((unsigned)f2bf(v.y) << 16);
    o.y = (unsigned)f2bf(v.z) | ((unsigned)f2bf(v.w) << 16);
  } else {
    o.x = 0u; o.y = 0u;
  }
  ((uint2*)(disp + (size_t)s * DIM))[tid] = o;
}

// ---------------- 4. transpose fp32 [R,C] -> bf16 [C,R] per expert ----------------
// 256 threads, 64col x 128row tile: per-wave stores are 4 x 256B contiguous runs
__global__ void transpose_cvt(const float* __restrict__ in, unsigned short* __restrict__ out,
                              int R, int C) {
  __shared__ float tile[128][65];
  const int e = blockIdx.z;
  const float* inp = in + (size_t)e * R * C;
  unsigned short* outp = out + (size_t)e * R * C;
  const int c0 = blockIdx.x * 64, r0 = blockIdx.y * 128;
  const int t = threadIdx.x;
#pragma unroll
  for (int i = 0; i < 8; ++i) {
    int idx = i * 256 + t;
    int r = idx >> 4, c4 = (idx & 15) * 4;
    float4 v = *(const float4*)(inp + (size_t)(r0 + r) * C + c0 + c4);
    tile[r][c4 + 0] = v.x; tile[r][c4 + 1] = v.y;
    tile[r][c4 + 2] = v.z; tile[r][c4 + 3] = v.w;
  }
  __syncthreads();
#pragma unroll
  for (int i = 0; i < 4; ++i) {
    int idx = i * 256 + t;            // 1024 items: (col, 8-row group)
    int c = idx >> 4, r8 = (idx & 15) * 8;
    unsigned short s[8];
#pragma unroll
    for (int j = 0; j < 8; ++j) s[j] = f2bf(tile[r8 + j][c]);
    uint4 o;
    o.x = (unsigned)s[0] | ((unsigned)s[1] << 16);
    o.y = (unsigned)s[2] | ((unsigned)s[3] << 16);
    o.z = (unsigned)s[4] | ((unsigned)s[5] << 16);
    o.w = (unsigned)s[6] | ((unsigned)s[7] << 16);
    *(uint4*)(outp + (size_t)(c0 + c) * R + r0 + r8) = o;
  }
}

// ---------------- 5/6. bf16 MFMA GEMM: ring-quadrant pipeline, 32x32x16 ----------
// A [M=1024][K], B [N][K] bf16, C [M][N] bf16, bias fp32 over N.
// 512 threads = 8 waves (2M x 4N). BK=64. 4 LDS half-slots per operand
// (2 parities x 2 halves). Per K-tile: 4 phases, ring (0,0)(0,1)(1,1)(1,0);
// each operand-half is ds_read ONCE per tile (frags cached in regs).
// R2 bug fixed here: b0 is the ring's wrap operand (used ph0 AND ph3), so its
// refill for tile t+1 must issue AFTER ph3's MFMA — the ds_read's WAR on the
// b0 registers pins the order; its data is consumed only at ph0(t+1), one
// barrier later, so no exposed latency.
// Stage map: ph0(t) -> A0,B0,B1(t+1); ph2(t) -> A1(t+1).
// Waits:     ph0-end vmcnt(LA+2*LB) forces A1(t);  ph2-end vmcnt(LA) forces
//            the (t+1) 3-group. Last tile drains. All slot overwrites are
//            >=3 barriers after that slot's final ds_read (audited).
// LDS swizzle: chunk16 phys = logical ^ (row&7), pre-applied on the global
// source column; reads XOR it back (row&7 == lane&7 everywhere).
template <int BM, int BN, bool RELU>
__global__ __launch_bounds__(512, 1)
void gemm8(const unsigned short* __restrict__ A, const unsigned short* __restrict__ B,
           const float* __restrict__ bias, unsigned short* __restrict__ C,
           int N, int K) {
  constexpr int M = 1024;
  constexpr int FR = BM / 128;           // 32-row A frags per half per wave
  constexpr int ASLOT = (BM / 2) * 64;   // elems per A half-slot
  constexpr int BSLOT = (BN / 2) * 64;
  constexpr int LA = BM / 128;           // global_load_lds per thread per A half
  constexpr int LB = BN / 128;           // = 2
  static_assert(BN == 256, "FC==1 layout");

  extern __shared__ __align__(16) unsigned short smem[];
  unsigned short* As = smem;                  // 4 half-slots
  unsigned short* Bs = smem + 4 * ASLOT;      // 4 half-slots

  const int mt = M / BM;
  const int ntn = N / BN;
  // bijective XCD swizzle (grid % 8 == 0 for both instantiations)
  int bid = blockIdx.x;
  const int cpx = (int)gridDim.x >> 3;
  bid = (bid & 7) * cpx + (bid >> 3);
  const int e = bid / (mt * ntn);
  const int rb = bid - e * mt * ntn;
  const int mtile = rb / ntn;
  const int ntile = rb - mtile * ntn;

  A += (size_t)e * M * K;
  B += (size_t)e * N * K;
  bias += (size_t)e * N;
  C += (size_t)e * M * N;
  const int m0 = mtile * BM;
  const int n0 = ntile * BN;

  const int tid = threadIdx.x;
  const int w = tid >> 6, lane = tid & 63;
  const int wm = w >> 2, wn = w & 3;
  const int lane32 = lane & 31;
  const int khalf = lane >> 5;
  const int fx = lane & 7;

  // staging addresses: thread covers row w*8+(lane>>3), phys chunk lane&7,
  // loading swizzled logical chunk (lane&7)^(row&7)
  const int srow = lane >> 3;
  const int scol = ((lane & 7) ^ srow) * 8;
  const unsigned short* gA = A + (size_t)(m0 + w * 8 + srow) * K + scol;
  const unsigned short* gB = B + (size_t)(n0 + w * 8 + srow) * K + scol;
  const int lbase = w * 512;

  // fragment-read addressing
  int coff[4];
#pragma unroll
  for (int ks = 0; ks < 4; ++ks) coff[ks] = ((ks * 2 + khalf) ^ fx) * 8;
  int aoff[FR];
#pragma unroll
  for (int f = 0; f < FR; ++f) aoff[f] = (wm * (FR * 32) + f * 32 + lane32) * 64;
  const int boff = (wn * 32 + lane32) * 64;

  f32x16 acc[2][2][FR] = {};
  bf16x8 a0[FR][4], a1[FR][4], b0[4], b1[4];
  const int nt = K >> 6;

#define STAGE_A(T, MH, SLOT)                                                      \
  { _Pragma("unroll")                                                             \
    for (int q_ = 0; q_ < LA; ++q_)                                               \
      load_lds16(gA + (size_t)((MH) * (BM / 2) + q_ * 64) * K + (size_t)(T) * 64, \
                 &As[(SLOT) * ASLOT + lbase + q_ * 4096]); }

#define STAGE_B(T, NH, SLOT)                                                      \
  { _Pragma("unroll")                                                             \
    for (int q_ = 0; q_ < LB; ++q_)                                               \
      load_lds16(gB + (size_t)((NH) * (BN / 2) + q_ * 64) * K + (size_t)(T) * 64, \
                 &Bs[(SLOT) * BSLOT + lbase + q_ * 4096]); }

#define READ_A(dst, SLOT)                                                         \
  { _Pragma("unroll")                                                             \
    for (int f_ = 0; f_ < FR; ++f_)                                               \
      _Pragma("unroll")                                                           \
      for (int k_ = 0; k_ < 4; ++k_)                                              \
        dst[f_][k_] = *(const bf16x8*)&As[(SLOT) * ASLOT + aoff[f_] + coff[k_]]; }

#define READ_B(dst, SLOT)                                                         \
  { _Pragma("unroll")                                                             \
    for (int k_ = 0; k_ < 4; ++k_)                                                \
      dst[k_] = *(const bf16x8*)&Bs[(SLOT) * BSLOT + boff + coff[k_]]; }

#define MFMA_PH(MH, NH, AARR, BARR)                                               \
  { __builtin_amdgcn_s_setprio(1);                                               \
    _Pragma("unroll")                                                             \
    for (int f_ = 0; f_ < FR; ++f_)                                               \
      _Pragma("unroll")                                                           \
      for (int k_ = 0; k_ < 4; ++k_)                                              \
        acc[MH][NH][f_] = __builtin_amdgcn_mfma_f32_32x32x16_bf16(                \
            AARR[f_][k_], BARR[k_], acc[MH][NH][f_], 0, 0, 0);                    \
    __builtin_amdgcn_s_setprio(0); }

#define BARF() { __builtin_amdgcn_s_barrier(); asm volatile("" ::: "memory"); }

#define VMW_PH0(S1)                                                               \
  { if (S1) { if constexpr (LA == 2) asm volatile("s_waitcnt vmcnt(6)" ::: "memory"); \
              else                   asm volatile("s_waitcnt vmcnt(5)" ::: "memory"); } \
    else asm volatile("s_waitcnt vmcnt(0)" ::: "memory"); }

#define VMW_PH2()                                                                 \
  { if constexpr (LA == 2) asm volatile("s_waitcnt vmcnt(2)" ::: "memory");       \
    else                   asm volatile("s_waitcnt vmcnt(1)" ::: "memory"); }

#define TILE(T, P)                                                                \
  {                                                                               \
    const bool s1_ = (T) + 1 < nt;                                                \
    /* ph0: quadrant (0,0) */                                                     \
    READ_B(b1, 2 * (P) + 1);                                                      \
    if (s1_) {                                                                    \
      STAGE_A((T) + 1, 0, 2 * ((P) ^ 1));                                         \
      STAGE_B((T) + 1, 0, 2 * ((P) ^ 1));                                         \
      STAGE_B((T) + 1, 1, 2 * ((P) ^ 1) + 1);                                     \
    }                                                                             \
    MFMA_PH(0, 0, a0, b0);                                                        \
    VMW_PH0(s1_);                                                                 \
    BARF();                                                                       \
    /* ph1: quadrant (0,1) */                                                     \
    READ_A(a1, 2 * (P) + 1);                                                      \
    MFMA_PH(0, 1, a0, b1);                                                        \
    BARF();                                                                       \
    /* ph2: quadrant (1,1) */                                                     \
    if (s1_) { STAGE_A((T) + 1, 1, 2 * ((P) ^ 1) + 1); }                          \
    MFMA_PH(1, 1, a1, b1);                                                        \
    VMW_PH2();                                                                    \
    BARF();                                                                       \
    /* ph3: quadrant (1,0) — b0 refill must come AFTER its last use */            \
    if (s1_) { READ_A(a0, 2 * ((P) ^ 1)); }                                       \
    MFMA_PH(1, 0, a1, b0);                                                        \
    if (s1_) { READ_B(b0, 2 * ((P) ^ 1)); }                                       \
    BARF();                                                                       \
  }

  // prologue: stage tile 0 (order: A0,B0,B1 then A1), wait the first 3 groups
  STAGE_A(0, 0, 0); STAGE_B(0, 0, 0); STAGE_B(0, 1, 1);
  STAGE_A(0, 1, 1);
  if constexpr (LA == 2) asm volatile("s_waitcnt vmcnt(2)" ::: "memory");
  else                   asm volatile("s_waitcnt vmcnt(1)" ::: "memory");
  BARF();
  READ_A(a0, 0); READ_B(b0, 0);

  for (int t = 0; t < nt; t += 2) {
    TILE(t, 0);
    TILE(t + 1, 1);
  }

#undef TILE
#undef VMW_PH2
#undef VMW_PH0
#undef BARF
#undef MFMA_PH
#undef READ_B
#undef READ_A
#undef STAGE_B
#undef STAGE_A

  // ---- epilogue: restage per M-half -> coalesced dwordx4 stores ----
  asm volatile("s_waitcnt vmcnt(0)" ::: "memory");
  constexpr int SW = BN + 8;             // shorts: 528B row stride, 16B-aligned
  unsigned short* scr = smem;
  const int colw = wn * 32 + lane32;
#pragma unroll
  for (int Mh = 0; Mh < 2; ++Mh) {
    __syncthreads();
#pragma unroll
    for (int Nh = 0; Nh < 2; ++Nh) {
      float bv = bias[n0 + Nh * (BN / 2) + colw];
#pragma unroll
      for (int f = 0; f < FR; ++f)
#pragma unroll
        for (int r = 0; r < 16; ++r) {
          int rowin = (r & 3) + 8 * (r >> 2) + 4 * khalf;
          float v = acc[Mh][Nh][f][r] + bv;
          if (RELU) v = fmaxf(v, 0.f);
          scr[(wm * (FR * 32) + f * 32 + rowin) * SW + Nh * (BN / 2) + colw] = f2bf(v);
        }
    }
    __syncthreads();
#pragma unroll
    for (int it = 0; it < (BM / 2) * (BN / 8) / 512; ++it) {
      const int u = it * 512 + tid;
      const int row = u / (BN / 8), seg = u % (BN / 8);
      uint4 v = *(const uint4*)&scr[row * SW + seg * 8];
      *(uint4*)&C[(size_t)(m0 + Mh * (BM / 2) + row) * N + n0 + seg * 8] = v;
    }
  }
}

// ---------------- 7. combine: gate-weighted gather (bf16 expert out) ----------------
__global__ void combine_kernel(const unsigned short* __restrict__ outb,
                               const int* __restrict__ tok_e, const int* __restrict__ tok_loc,
                               const float* __restrict__ tok_g, float* __restrict__ y) {
  const int t = blockIdx.x;
  const int tid = threadIdx.x;  // 0..255, 4 bf16 each
  int e0 = tok_e[2 * t], e1 = tok_e[2 * t + 1];
  int l0 = tok_loc[2 * t], l1 = tok_loc[2 * t + 1];
  float g0 = tok_g[2 * t], g1 = tok_g[2 * t + 1];
  float ax = 0.f, ay = 0.f, az = 0.f, aw = 0.f;
  if (l0 >= 0) {
    uint2 u = ((const uint2*)(outb + ((size_t)e0 * CAP + l0) * DIM))[tid];
    ax += g0 * bf2f(u.x & 0xffffu); ay += g0 * __uint_as_float(u.x & 0xffff0000u);
    az += g0 * bf2f(u.y & 0xffffu); aw += g0 * __uint_as_float(u.y & 0xffff0000u);
  }
  if (l1 >= 0) {
    uint2 u = ((const uint2*)(outb + ((size_t)e1 * CAP + l1) * DIM))[tid];
    ax += g1 * bf2f(u.x & 0xffffu); ay += g1 * __uint_as_float(u.x & 0xffff0000u);
    az += g1 * bf2f(u.y & 0xffffu); aw += g1 * __uint_as_float(u.y & 0xffff0000u);
  }
  float4 o; o.x = ax; o.y = ay; o.z = az; o.w = aw;
  ((float4*)(y + (size_t)t * DIM))[tid] = o;
}

extern "C" void kernel_launch(void* const* d_in, const int* in_sizes, int n_in,
                              void* d_out, int out_size, void* d_ws, size_t ws_size,
                              hipStream_t stream) {
  const float* x  = (const float*)d_in[0];
  const float* wg = (const float*)d_in[1];
  const float* w1 = (const float*)d_in[2];
  const float* b1 = (const float*)d_in[3];
  const float* w2 = (const float*)d_in[4];
  const float* b2 = (const float*)d_in[5];
  float* y = (float*)d_out;

  char* ws = (char*)d_ws;
  int*   tok_e    = (int*)(ws);
  int*   tok_loc  = (int*)(ws + 32768);
  float* tok_g    = (float*)(ws + 65536);
  int*   slot_map = (int*)(ws + 98304);
  unsigned short* disp = (unsigned short*)(ws + 131072);                      // 16 MiB
  unsigned short* wbuf = (unsigned short*)(ws + 131072 + (16ull << 20));      // 64 MiB
  unsigned short* h    = (unsigned short*)(ws + 131072 + (80ull << 20));      // 64 MiB
  unsigned short* outb = (unsigned short*)(ws + 131072 + (144ull << 20));     // 16 MiB

  // one-time: allow >64 KiB dynamic LDS for the pipelined GEMMs
  static int att = 0;
  if (!att) {
    (void)hipFuncSetAttribute(reinterpret_cast<const void*>(&gemm8<256, 256, true>),
                              hipFuncAttributeMaxDynamicSharedMemorySize, 131072);
    (void)hipFuncSetAttribute(reinterpret_cast<const void*>(&gemm8<128, 256, false>),
                              hipFuncAttributeMaxDynamicSharedMemorySize, 98304);
    att = 1;
  }

  gating_kernel<<<NTOK, 64, 0, stream>>>(x, wg, tok_e, tok_g);
  scan_kernel<<<1, 64, 0, stream>>>(tok_e, tok_loc, slot_map);
  dispatch_kernel<<<NEXP * CAP, 256, 0, stream>>>(x, slot_map, disp);
  // w1 [E][D][H] -> wbuf [E][H][D] bf16
  transpose_cvt<<<dim3(HID / 64, DIM / 128, NEXP), 256, 0, stream>>>(w1, wbuf, DIM, HID);
  // h = relu(disp @ w1 + b1): M=1024, N=HID, K=DIM; 512 blocks
  gemm8<256, 256, true><<<NEXP * (1024 / 256) * (HID / 256), 512, 131072, stream>>>(
      disp, wbuf, b1, h, HID, DIM);
  // w2 [E][H][D] -> wbuf [E][D][H] bf16
  transpose_cvt<<<dim3(DIM / 64, HID / 128, NEXP), 256, 0, stream>>>(w2, wbuf, HID, DIM);
  // out = h @ w2 + b2: M=1024, N=DIM, K=HID; 256 blocks
  gemm8<128, 256, false><<<NEXP * (1024 / 128) * (DIM / 256), 512, 98304, stream>>>(
      h, wbuf, b2, outb, DIM, HID);
  combine_kernel<<<NTOK, 256, 0, stream>>>(outb, tok_e, tok_loc, tok_g, y);
}